// Round 3
// baseline (356.400 us; speedup 1.0000x reference)
//
#include <hip/hip_runtime.h>

#define H_   256
#define W_   256
#define HW_  65536
#define C_   256
#define MID  16
#define B_   2

// ---------------------------------------------------------------------------
// K0: one tiny block. Computes the 4 normalized anisotropic Gaussian 7x7
// kernels into ws (196 floats).
// ---------------------------------------------------------------------------
__global__ __launch_bounds__(256) void k0_prep(float* __restrict__ base_out) {
    __shared__ float s_k[4][49];
    __shared__ float s_inv[4];
    int t = threadIdx.x;
    if (t < 196) {
        int k = t / 49, p = t % 49;
        int i = p / 7, j = p % 7;
        float xx = (float)(i - 3), yy = (float)(j - 3);
        const float cs[4] = {1.0f, 0.70710678118654752f, 0.0f, -0.70710678118654752f};
        const float sn[4] = {0.0f, 0.70710678118654752f, 1.0f, 0.70710678118654752f};
        float c = cs[k], s = sn[k];
        float xr = xx * c + yy * s;
        float yr = -xx * s + yy * c;
        float v = expf(-(xr * xr * 0.08f + yr * yr * 0.5f));
        s_k[k][p] = v;
    }
    __syncthreads();
    if (t < 4) {
        float s = 0.f;
        for (int p = 0; p < 49; ++p) s += s_k[t][p];
        s_inv[t] = 1.0f / s;
    }
    __syncthreads();
    if (t < 196) base_out[t] = s_k[t / 49][t % 49] * s_inv[t / 49];
}

// ---------------------------------------------------------------------------
// kA: x_low (planar) [b][m][h*W+w] = sum_c x[b,c,h,w] * rw[m][c]
// 512 blocks (b,h row) x 256 thr (w). 32-deep nontemporal load pipeline;
// weights via uniform scalar loads straight from rw (K$-resident rows).
// ---------------------------------------------------------------------------
__global__ __launch_bounds__(256) void kA_reduce(const float* __restrict__ x,
                                                 const float* __restrict__ rw,
                                                 float* __restrict__ xlow) {
    int bh = blockIdx.x;
    int b = bh >> 8, h = bh & 255;
    int w = threadIdx.x;
    const float* xp = x + (size_t)b * C_ * HW_ + h * W_ + w;
    float acc[MID];
#pragma unroll
    for (int m = 0; m < MID; ++m) acc[m] = 0.f;
    for (int cb = 0; cb < C_; cb += 32) {
        float xv[32];
#pragma unroll
        for (int i = 0; i < 32; ++i)
            xv[i] = __builtin_nontemporal_load(xp + (size_t)(cb + i) * HW_);
#pragma unroll
        for (int i = 0; i < 32; ++i) {
#pragma unroll
            for (int m = 0; m < MID; ++m)
                acc[m] = fmaf(rw[m * C_ + cb + i], xv[i], acc[m]);
        }
    }
    float* op = xlow + (size_t)b * MID * HW_ + h * W_ + w;
#pragma unroll
    for (int m = 0; m < MID; ++m) op[(size_t)m * HW_] = acc[m];
}

// ---------------------------------------------------------------------------
// kBC: fused per-pixel MLP -> softmax -> blended 7x7 directional conv over
// 16 channels (planar, lane-coalesced gathers) -> 16->256 expand ->
// nontemporal streamed stores. 512 blocks = (b,h); 256 thr = w. No barriers,
// so waves skew and the conv L1 phase hides under the write-BW-bound expand.
// ---------------------------------------------------------------------------
__global__ __launch_bounds__(256) void kBC_conv_expand(
        const float* __restrict__ xlow,
        const float* __restrict__ base,
        const float* __restrict__ angle,
        const float* __restrict__ w1,
        const float* __restrict__ b1,
        const float* __restrict__ w2,
        const float* __restrict__ b2,
        const float* __restrict__ ew,
        float* __restrict__ out) {
    int bh = blockIdx.x;
    int b = bh >> 8, h = bh & 255;
    int w = threadIdx.x;

    // ---- MLP + softmax -> wk[4] ----
    float a2 = 2.0f * angle[(size_t)b * HW_ + h * W_ + w];
    float f0 = __sinf(a2), f1 = __cosf(a2);
    float hb[8];
#pragma unroll
    for (int j = 0; j < 8; ++j)
        hb[j] = fmaxf(fmaf(w1[j * 2], f0, fmaf(w1[j * 2 + 1], f1, b1[j])), 0.f);
    float lg[4];
#pragma unroll
    for (int k = 0; k < 4; ++k) {
        float s = b2[k];
#pragma unroll
        for (int j = 0; j < 8; ++j) s = fmaf(w2[k * 8 + j], hb[j], s);
        lg[k] = s;
    }
    float mx = fmaxf(fmaxf(lg[0], lg[1]), fmaxf(lg[2], lg[3]));
    float wk[4];
    float ssum = 0.f;
#pragma unroll
    for (int k = 0; k < 4; ++k) { wk[k] = __expf(lg[k] - mx); ssum += wk[k]; }
    float inv = 1.0f / ssum;
#pragma unroll
    for (int k = 0; k < 4; ++k) wk[k] *= inv;

    // ---- 7x7 directional conv, 16 channels, reflect padding ----
    int cc[7];
#pragma unroll
    for (int dx = 0; dx < 7; ++dx) {
        int c0 = w + dx - 3;
        cc[dx] = c0 < 0 ? -c0 : (c0 > 255 ? 510 - c0 : c0);
    }
    float acc[MID];
#pragma unroll
    for (int m = 0; m < MID; ++m) acc[m] = 0.f;
    const float* xb = xlow + (size_t)b * MID * HW_;
    for (int dy = 0; dy < 7; ++dy) {
        int hy = h + dy - 3;
        hy = hy < 0 ? -hy : (hy > 255 ? 510 - hy : hy);
        float e[7];
#pragma unroll
        for (int dx = 0; dx < 7; ++dx) {
            int tp = dy * 7 + dx;
            e[dx] = fmaf(wk[0], base[tp],
                    fmaf(wk[1], base[49 + tp],
                    fmaf(wk[2], base[98 + tp], wk[3] * base[147 + tp])));
        }
        const float* rowb = xb + (size_t)hy * W_;
#pragma unroll
        for (int m = 0; m < MID; ++m) {
            const float* row = rowb + (size_t)m * HW_;
            float s = acc[m];
#pragma unroll
            for (int dx = 0; dx < 7; ++dx) s = fmaf(e[dx], row[cc[dx]], s);
            acc[m] = s;
        }
    }

    // ---- expand 16 -> 256, streamed out ----
    float* ob = out + (size_t)b * C_ * HW_ + h * W_ + w;
#pragma unroll 4
    for (int c = 0; c < C_; ++c) {
        const float* wc = ew + (size_t)c * MID;
        float s = wc[0] * acc[0];
#pragma unroll
        for (int m = 1; m < MID; ++m) s = fmaf(wc[m], acc[m], s);
        __builtin_nontemporal_store(s, ob + (size_t)c * HW_);
    }
}

// ---------------------------------------------------------------------------
extern "C" void kernel_launch(void* const* d_in, const int* in_sizes, int n_in,
                              void* d_out, int out_size, void* d_ws, size_t ws_size,
                              hipStream_t stream) {
    const float* x     = (const float*)d_in[0];
    const float* angle = (const float*)d_in[1];
    const float* rw    = (const float*)d_in[2];
    const float* ew    = (const float*)d_in[3];
    const float* w1    = (const float*)d_in[4];
    const float* b1    = (const float*)d_in[5];
    const float* w2    = (const float*)d_in[6];
    const float* b2    = (const float*)d_in[7];
    float* out = (float*)d_out;

    float* wsf  = (float*)d_ws;
    float* base = wsf;            // 196 floats
    float* xlow = wsf + 256;      // 2*16*65536 floats, planar [b][m][hw]

    hipLaunchKernelGGL(k0_prep,   dim3(1),   dim3(256), 0, stream, base);
    hipLaunchKernelGGL(kA_reduce, dim3(512), dim3(256), 0, stream, x, rw, xlow);
    hipLaunchKernelGGL(kBC_conv_expand, dim3(512), dim3(256), 0, stream,
                       xlow, base, angle, w1, b1, w2, b2, ew, out);
}

// Round 6
// 285.768 us; speedup vs baseline: 1.2472x; 1.2472x over previous
//
#include <hip/hip_runtime.h>

#define H_   256
#define W_   256
#define HW_  65536
#define C_   256
#define MID  16
#define B_   2

// ---------------------------------------------------------------------------
// K0: 4 normalized anisotropic Gaussian 7x7 kernels (196 floats).
// ---------------------------------------------------------------------------
__global__ __launch_bounds__(256) void k0_prep(float* __restrict__ base_out) {
    __shared__ float s_k[4][49];
    __shared__ float s_inv[4];
    int t = threadIdx.x;
    if (t < 196) {
        int k = t / 49, p = t % 49;
        int i = p / 7, j = p % 7;
        float xx = (float)(i - 3), yy = (float)(j - 3);
        const float cs[4] = {1.0f, 0.70710678118654752f, 0.0f, -0.70710678118654752f};
        const float sn[4] = {0.0f, 0.70710678118654752f, 1.0f, 0.70710678118654752f};
        float c = cs[k], s = sn[k];
        float xr = xx * c + yy * s;
        float yr = -xx * s + yy * c;
        float v = expf(-(xr * xr * 0.08f + yr * yr * 0.5f));
        s_k[k][p] = v;
    }
    __syncthreads();
    if (t < 4) {
        float s = 0.f;
        for (int p = 0; p < 49; ++p) s += s_k[t][p];
        s_inv[t] = 1.0f / s;
    }
    __syncthreads();
    if (t < 196) base_out[t] = s_k[t / 49][t % 49] * s_inv[t / 49];
}

// ---------------------------------------------------------------------------
// kA: partial channel reduction. c-split 4 x 2px/thread (8B loads).
// grid 1024 blocks (cq(4) x b(2) x double-row(128)) x 256 thr = 16 waves/CU.
// part[cq][b][m][hw] planar.
// ---------------------------------------------------------------------------
__global__ __launch_bounds__(256) void kA_reduce(const float* __restrict__ x,
                                                 const float* __restrict__ rw,
                                                 float* __restrict__ part) {
    int bid = blockIdx.x;
    int cq = bid & 3;
    int rest = bid >> 2;           // [0,256)
    int b = rest >> 7, hh = rest & 127;
    int t = threadIdx.x;
    int pix = hh * 512 + 2 * t;    // double-row of 512 pixels
    const unsigned long long* xp =
        (const unsigned long long*)(x + (size_t)b * C_ * HW_ + (size_t)cq * 64 * HW_ + pix);
    const float* wp = rw + cq * 64;
    float accx[MID], accy[MID];
#pragma unroll
    for (int m = 0; m < MID; ++m) { accx[m] = 0.f; accy[m] = 0.f; }
    for (int cb = 0; cb < 64; cb += 16) {
        unsigned long long xv[16];
#pragma unroll
        for (int i = 0; i < 16; ++i)
            xv[i] = __builtin_nontemporal_load(xp + (size_t)(cb + i) * (HW_ / 2));
#pragma unroll
        for (int i = 0; i < 16; ++i) {
            float vx = __uint_as_float((unsigned)(xv[i] & 0xffffffffull));
            float vy = __uint_as_float((unsigned)(xv[i] >> 32));
#pragma unroll
            for (int m = 0; m < MID; ++m) {
                float wv = wp[m * C_ + cb + i];   // uniform -> s_load
                accx[m] = fmaf(wv, vx, accx[m]);
                accy[m] = fmaf(wv, vy, accy[m]);
            }
        }
    }
    float2* op = (float2*)(part + (((size_t)cq * B_ + b) * MID) * HW_ + pix);
#pragma unroll
    for (int m = 0; m < MID; ++m) op[m * (HW_ / 2)] = make_float2(accx[m], accy[m]);
}

// ---------------------------------------------------------------------------
// kS: xlow = part0 + part1 + part2 + part3 (planar, float4 stream).
// 2048 blocks x 256 thr.
// ---------------------------------------------------------------------------
__global__ __launch_bounds__(256) void kS_sum(const float* __restrict__ part,
                                              float* __restrict__ xlow) {
    size_t i = (size_t)blockIdx.x * 256 + threadIdx.x;   // float4 index
    const size_t stride = (size_t)B_ * MID * HW_ / 4;    // 524288
    const float4* p = (const float4*)part;
    float4 a = p[i];
    float4 b = p[i + stride];
    float4 c = p[i + 2 * stride];
    float4 d = p[i + 3 * stride];
    float4 r;
    r.x = (a.x + b.x) + (c.x + d.x);
    r.y = (a.y + b.y) + (c.y + d.y);
    r.z = (a.z + b.z) + (c.z + d.z);
    r.w = (a.w + b.w) + (c.w + d.w);
    ((float4*)xlow)[i] = r;
}

// ---------------------------------------------------------------------------
// kB: per-pixel MLP -> softmax -> blended 7x7 conv over 16 planar channels
// (lane-coalesced L1 gathers) -> olow px-major [b][hw][16].
// 512 blocks (b,h) x 256 thr (w).
// ---------------------------------------------------------------------------
__global__ __launch_bounds__(256) void kB_conv(const float* __restrict__ xlow,
                                               const float* __restrict__ base,
                                               const float* __restrict__ angle,
                                               const float* __restrict__ w1,
                                               const float* __restrict__ b1,
                                               const float* __restrict__ w2,
                                               const float* __restrict__ b2,
                                               float* __restrict__ olow) {
    int bh = blockIdx.x;
    int b = bh >> 8, h = bh & 255;
    int w = threadIdx.x;

    // ---- MLP + softmax -> wk[4] ----
    float a2 = 2.0f * angle[(size_t)b * HW_ + h * W_ + w];
    float f0 = __sinf(a2), f1 = __cosf(a2);
    float hb[8];
#pragma unroll
    for (int j = 0; j < 8; ++j)
        hb[j] = fmaxf(fmaf(w1[j * 2], f0, fmaf(w1[j * 2 + 1], f1, b1[j])), 0.f);
    float lg[4];
#pragma unroll
    for (int k = 0; k < 4; ++k) {
        float s = b2[k];
#pragma unroll
        for (int j = 0; j < 8; ++j) s = fmaf(w2[k * 8 + j], hb[j], s);
        lg[k] = s;
    }
    float mx = fmaxf(fmaxf(lg[0], lg[1]), fmaxf(lg[2], lg[3]));
    float wk[4];
    float ssum = 0.f;
#pragma unroll
    for (int k = 0; k < 4; ++k) { wk[k] = __expf(lg[k] - mx); ssum += wk[k]; }
    float inv = 1.0f / ssum;
#pragma unroll
    for (int k = 0; k < 4; ++k) wk[k] *= inv;

    // ---- 7x7 conv, reflect padding, planar reads ----
    int cc[7];
#pragma unroll
    for (int dx = 0; dx < 7; ++dx) {
        int c0 = w + dx - 3;
        cc[dx] = c0 < 0 ? -c0 : (c0 > 255 ? 510 - c0 : c0);
    }
    float acc[MID];
#pragma unroll
    for (int m = 0; m < MID; ++m) acc[m] = 0.f;
    const float* xb = xlow + (size_t)b * MID * HW_;
    for (int dy = 0; dy < 7; ++dy) {
        int hy = h + dy - 3;
        hy = hy < 0 ? -hy : (hy > 255 ? 510 - hy : hy);
        float e[7];
#pragma unroll
        for (int dx = 0; dx < 7; ++dx) {
            int tp = dy * 7 + dx;
            e[dx] = fmaf(wk[0], base[tp],
                    fmaf(wk[1], base[49 + tp],
                    fmaf(wk[2], base[98 + tp], wk[3] * base[147 + tp])));
        }
        const float* rowb = xb + (size_t)hy * W_;
#pragma unroll
        for (int m = 0; m < MID; ++m) {
            const float* row = rowb + (size_t)m * HW_;
            float s = acc[m];
#pragma unroll
            for (int dx = 0; dx < 7; ++dx) s = fmaf(e[dx], row[cc[dx]], s);
            acc[m] = s;
        }
    }

    float4* op = (float4*)(olow + ((size_t)b * HW_ + h * W_ + w) * MID);
    op[0] = make_float4(acc[0], acc[1], acc[2], acc[3]);
    op[1] = make_float4(acc[4], acc[5], acc[6], acc[7]);
    op[2] = make_float4(acc[8], acc[9], acc[10], acc[11]);
    op[3] = make_float4(acc[12], acc[13], acc[14], acc[15]);
}

// ---------------------------------------------------------------------------
// kC: expand 16->256, c-split 4 -> 2048 blocks = 32 waves/CU, write-stream.
// bid: cq = bid&3, h = (bid>>2)&255, b = bid>>10.
// ---------------------------------------------------------------------------
__global__ __launch_bounds__(256) void kC_expand(const float* __restrict__ olow,
                                                 const float* __restrict__ ew,
                                                 float* __restrict__ out) {
    int bid = blockIdx.x;
    int cq = bid & 3;
    int h = (bid >> 2) & 255;
    int b = bid >> 10;
    int w = threadIdx.x;
    const float4* ip = (const float4*)(olow + ((size_t)b * HW_ + h * W_ + w) * MID);
    float4 m0 = ip[0], m1 = ip[1], m2 = ip[2], m3 = ip[3];
    float* ob = out + ((size_t)b * C_ + cq * 64) * HW_ + h * W_ + w;
    const float* wb = ew + (size_t)cq * 64 * MID;
#pragma unroll 8
    for (int ci = 0; ci < 64; ++ci) {
        const float* wc = wb + ci * MID;
        float s;
        s = wc[0] * m0.x;
        s = fmaf(wc[1], m0.y, s);
        s = fmaf(wc[2], m0.z, s);
        s = fmaf(wc[3], m0.w, s);
        s = fmaf(wc[4], m1.x, s);
        s = fmaf(wc[5], m1.y, s);
        s = fmaf(wc[6], m1.z, s);
        s = fmaf(wc[7], m1.w, s);
        s = fmaf(wc[8], m2.x, s);
        s = fmaf(wc[9], m2.y, s);
        s = fmaf(wc[10], m2.z, s);
        s = fmaf(wc[11], m2.w, s);
        s = fmaf(wc[12], m3.x, s);
        s = fmaf(wc[13], m3.y, s);
        s = fmaf(wc[14], m3.z, s);
        s = fmaf(wc[15], m3.w, s);
        __builtin_nontemporal_store(s, ob + (size_t)ci * HW_);
    }
}

// ---------------------------------------------------------------------------
extern "C" void kernel_launch(void* const* d_in, const int* in_sizes, int n_in,
                              void* d_out, int out_size, void* d_ws, size_t ws_size,
                              hipStream_t stream) {
    const float* x     = (const float*)d_in[0];
    const float* angle = (const float*)d_in[1];
    const float* rw    = (const float*)d_in[2];
    const float* ew    = (const float*)d_in[3];
    const float* w1    = (const float*)d_in[4];
    const float* b1    = (const float*)d_in[5];
    const float* w2    = (const float*)d_in[6];
    const float* b2    = (const float*)d_in[7];
    float* out = (float*)d_out;

    float* wsf  = (float*)d_ws;
    float* base = wsf;                               // 196 floats
    float* xlow = wsf + 256;                         // 2M floats, planar
    float* olow = xlow + (size_t)B_ * MID * HW_;     // 2M floats, px-major
    float* part = olow + (size_t)B_ * MID * HW_;     // 8M floats

    hipLaunchKernelGGL(k0_prep,   dim3(1),    dim3(256), 0, stream, base);
    hipLaunchKernelGGL(kA_reduce, dim3(1024), dim3(256), 0, stream, x, rw, part);
    hipLaunchKernelGGL(kS_sum,    dim3(2048), dim3(256), 0, stream, part, xlow);
    hipLaunchKernelGGL(kB_conv,   dim3(512),  dim3(256), 0, stream,
                       xlow, base, angle, w1, b1, w2, b2, olow);
    hipLaunchKernelGGL(kC_expand, dim3(2048), dim3(256), 0, stream, olow, ew, out);
}